// Round 5
// baseline (514.111 us; speedup 1.0000x reference)
//
#include <hip/hip_runtime.h>
#include <hip/hip_fp16.h>

#define DIN 128
#define DOUT 32
#define SLOPE 0.2f

#define BSHIFT 7                 // 128 nodes per bucket
#define BNODES 128
#define NBMAX  800               // >= ceil(100000/128)=782
#define CAP    3072              // bucket capacity (lambda ~2048, 20+ sigma)
#define TILE   8192              // edges per bin block

typedef short s16x8 __attribute__((ext_vector_type(8)));   // 8 bf16 (4 VGPRs)
typedef float f32x4 __attribute__((ext_vector_type(4)));   // MFMA C/D frag

__device__ __forceinline__ short f2bf(float f) {          // fp32 -> bf16 (RNE)
    unsigned u = __float_as_uint(f);
    return (short)((u + 0x7fffu + ((u >> 16) & 1u)) >> 16);
}
__device__ __forceinline__ float bf2f(short s) {
    return __uint_as_float(((unsigned)(unsigned short)s) << 16);
}

// ---------------- Linear role: one wave computes 16 rows of h via MFMA -------
// hi/lo bf16 split both sides, 3 MFMAs per tile => fp32-level accuracy.
__device__ __forceinline__ void linear_role(
    int tile, int ntiles, int lane, int N,
    const float* __restrict__ x, const float* __restrict__ W,
    const float* __restrict__ b, const float* __restrict__ a2,
    __half* __restrict__ g16, float* __restrict__ es2)
{
    if (tile >= ntiles) return;
    int m = lane & 15, oct = lane >> 4;
    long rowbase = (long)tile * 16;

    s16x8 bh[2][4], bl[2][4];
    #pragma unroll
    for (int t = 0; t < 2; ++t) {
        const float* wrow = W + (long)(t * 16 + m) * DIN + oct * 8;
        #pragma unroll
        for (int kc = 0; kc < 4; ++kc) {
            float4 w0 = *(const float4*)(wrow + kc * 32);
            float4 w1 = *(const float4*)(wrow + kc * 32 + 4);
            float wf[8] = {w0.x, w0.y, w0.z, w0.w, w1.x, w1.y, w1.z, w1.w};
            #pragma unroll
            for (int j = 0; j < 8; ++j) {
                short hh = f2bf(wf[j]);
                bh[t][kc][j] = hh;
                bl[t][kc][j] = f2bf(wf[j] - bf2f(hh));
            }
        }
    }

    long lrow = rowbase + m; if (lrow > N - 1) lrow = N - 1;   // load clamp
    const float* xrow = x + lrow * DIN + oct * 8;
    f32x4 acc0 = {0.f, 0.f, 0.f, 0.f}, acc1 = {0.f, 0.f, 0.f, 0.f};
    #pragma unroll
    for (int kc = 0; kc < 4; ++kc) {
        float4 x0 = *(const float4*)(xrow + kc * 32);
        float4 x1 = *(const float4*)(xrow + kc * 32 + 4);
        float xf[8] = {x0.x, x0.y, x0.z, x0.w, x1.x, x1.y, x1.z, x1.w};
        s16x8 ah, al;
        #pragma unroll
        for (int j = 0; j < 8; ++j) {
            short hh = f2bf(xf[j]);
            ah[j] = hh;
            al[j] = f2bf(xf[j] - bf2f(hh));
        }
        acc0 = __builtin_amdgcn_mfma_f32_16x16x32_bf16(al, bh[0][kc], acc0, 0, 0, 0);
        acc0 = __builtin_amdgcn_mfma_f32_16x16x32_bf16(ah, bl[0][kc], acc0, 0, 0, 0);
        acc0 = __builtin_amdgcn_mfma_f32_16x16x32_bf16(ah, bh[0][kc], acc0, 0, 0, 0);
        acc1 = __builtin_amdgcn_mfma_f32_16x16x32_bf16(al, bh[1][kc], acc1, 0, 0, 0);
        acc1 = __builtin_amdgcn_mfma_f32_16x16x32_bf16(ah, bl[1][kc], acc1, 0, 0, 0);
        acc1 = __builtin_amdgcn_mfma_f32_16x16x32_bf16(ah, bh[1][kc], acc1, 0, 0, 0);
    }

    int c0 = m, c1 = 16 + m;
    float b0 = b[c0], b1 = b[c1], A0 = a2[c0], A1 = a2[c1];
    float hv0[4], hv1[4], sp[4];
    #pragma unroll
    for (int i = 0; i < 4; ++i) {
        hv0[i] = acc0[i] + b0;
        hv1[i] = acc1[i] + b1;
        float z0 = hv0[i] > 0.f ? hv0[i] : SLOPE * hv0[i];
        float z1 = hv1[i] > 0.f ? hv1[i] : SLOPE * hv1[i];
        sp[i] = z0 * A0 + z1 * A1;
    }
    #pragma unroll
    for (int off = 1; off <= 8; off <<= 1) {
        #pragma unroll
        for (int i = 0; i < 4; ++i) sp[i] += __shfl_xor(sp[i], off, 64);
    }
    #pragma unroll
    for (int i = 0; i < 4; ++i) {
        long r = rowbase + oct * 4 + i;
        if (r >= N) continue;
        float ev = __expf(sp[i]);              // shift-invariant softmax: no max pass
        g16[r * DOUT + c0] = __float2half(ev * hv0[i]);
        g16[r * DOUT + c1] = __float2half(ev * hv1[i]);
        if (m == 0) es2[r] = ev;
    }
}

// ---------------- Fused kernel: linear blocks + edge-binning blocks ----------
// Bin: group edges by src-bucket (128 nodes). Record = (src&127)<<17 | dst.
// LDS-staged counting => each block writes ~10-record contiguous runs per
// bucket; per-XCD L2 merges partial lines (working set ~100KB/block).
__global__ __launch_bounds__(256) void gat_fused(
    const float* __restrict__ x, const float* __restrict__ W,
    const float* __restrict__ b, const float* __restrict__ a2,
    const int* __restrict__ src, const int* __restrict__ dst,
    __half* __restrict__ g16, float* __restrict__ es2,
    unsigned* __restrict__ ebuf, int* __restrict__ gcursor,
    int N, int E, int ntiles, int nlin, int NB)
{
    if ((int)blockIdx.x < nlin) {
        int wave = threadIdx.x >> 6;
        int tile = blockIdx.x * 4 + wave;
        linear_role(tile, ntiles, threadIdx.x & 63, N, x, W, b, a2, g16, es2);
        return;
    }
    __shared__ int cnt[NBMAX];
    __shared__ int base[NBMAX];
    int tid = threadIdx.x;
    int tstart = (blockIdx.x - nlin) * TILE;

    for (int i = tid; i < NB; i += 256) cnt[i] = 0;
    __syncthreads();
    #pragma unroll 4
    for (int it = 0; it < TILE / 256; ++it) {
        int e = tstart + it * 256 + tid;
        if (e < E) atomicAdd(&cnt[src[e] >> BSHIFT], 1);
    }
    __syncthreads();
    for (int i = tid; i < NB; i += 256) {
        base[i] = atomicAdd(&gcursor[i], cnt[i]);
        cnt[i] = 0;
    }
    __syncthreads();
    #pragma unroll 4
    for (int it = 0; it < TILE / 256; ++it) {
        int e = tstart + it * 256 + tid;
        if (e < E) {
            int s = src[e];
            int bk = s >> BSHIFT;
            int pos = base[bk] + atomicAdd(&cnt[bk], 1);
            if (pos < CAP)
                ebuf[(size_t)bk * CAP + pos] = ((unsigned)(s & (BNODES - 1)) << 17)
                                             | (unsigned)dst[e];
        }
    }
}

// ---------------- Aggregate: one block per bucket, fp32 LDS accumulators -----
// Records read coalesced; only g16 row gathers remain random.
__global__ __launch_bounds__(512) void gat_aggregate(
    const __half* __restrict__ g16, const float* __restrict__ es2,
    const unsigned* __restrict__ ebuf, const int* __restrict__ gcursor,
    float* __restrict__ out, int N)
{
    __shared__ float acc[BNODES * 32];   // 16 KB
    __shared__ float accd[BNODES];
    int tid = threadIdx.x;
    int bk = blockIdx.x;

    for (int i = tid; i < BNODES * 32; i += 512) acc[i] = 0.f;
    if (tid < BNODES) accd[tid] = 0.f;
    __syncthreads();

    int cnt = gcursor[bk]; if (cnt > CAP) cnt = CAP;
    int unit = tid >> 5, col = tid & 31;          // 16 half-wave units
    const unsigned* eb = ebuf + (size_t)bk * CAP;

    for (int r = unit; r < cnt; r += 16) {
        unsigned u = eb[r];                        // broadcast, sequential lines
        int sl = (int)(u >> 17);
        int dn = (int)(u & 0x1FFFFu);
        float gv = __half2float(g16[(long)dn * DOUT + col]);  // random 64B row
        atomicAdd(&acc[sl * 32 + col], gv);        // ds_add, conflict-free banks
        if (col == 0) atomicAdd(&accd[sl], es2[dn]);
    }
    __syncthreads();

    for (int sl = unit; sl < BNODES; sl += 16) {
        long node = (long)bk * BNODES + sl;
        if (node >= N) break;
        float gs = __half2float(g16[node * DOUT + col]);   // self-loop
        float d = accd[sl] + es2[node];
        out[node * DOUT + col] = (acc[sl * 32 + col] + gs) / d;
    }
}

extern "C" void kernel_launch(void* const* d_in, const int* in_sizes, int n_in,
                              void* d_out, int out_size, void* d_ws, size_t ws_size,
                              hipStream_t stream)
{
    const float* x  = (const float*)d_in[0];
    const int*   ei = (const int*)d_in[1];
    const float* W  = (const float*)d_in[2];
    const float* b  = (const float*)d_in[3];
    // d_in[4] = a1_w: unused — s1 cancels inside the segment softmax.
    const float* a2 = (const float*)d_in[5];
    float* out = (float*)d_out;

    int N = in_sizes[0] / DIN;
    int E = in_sizes[1] / 2;
    const int* src = ei;
    const int* dst = ei + E;

    int NB = (N + BNODES - 1) >> BSHIFT;      // 782

    char* ws = (char*)d_ws;
    __half*   g16    = (__half*)ws;   ws += (size_t)N * DOUT * sizeof(__half);
    float*    es2    = (float*)ws;    ws += (size_t)N * sizeof(float);
    int*      gcursor= (int*)ws;      ws += (size_t)NBMAX * sizeof(int);
    unsigned* ebuf   = (unsigned*)ws; ws += (size_t)NB * CAP * sizeof(unsigned);

    int ntiles = (N + 15) / 16;               // 6250
    int nlin   = (ntiles + 3) / 4;            // 1563 linear blocks (4 waves)
    int nbin   = (E + TILE - 1) / TILE;       // 196 bin blocks

    hipMemsetAsync(gcursor, 0, (size_t)NBMAX * sizeof(int), stream);
    gat_fused    <<<nlin + nbin, 256, 0, stream>>>(x, W, b, a2, src, dst,
                                                   g16, es2, ebuf, gcursor,
                                                   N, E, ntiles, nlin, NB);
    gat_aggregate<<<NB, 512, 0, stream>>>(g16, es2, ebuf, gcursor, out, N);
}

// Round 6
// 502.998 us; speedup vs baseline: 1.0221x; 1.0221x over previous
//
#include <hip/hip_runtime.h>
#include <hip/hip_fp16.h>

#define DIN 128
#define DOUT 32
#define SLOPE 0.2f

#define BSHIFT 7                 // 128 nodes per bucket
#define BNODES 128
#define NBMAX  800               // >= ceil(100000/128)=782
#define CAP    3072              // bucket capacity (lambda ~2048, 20+ sigma)
#define TILE   4096              // edges per bin block

typedef short s16x8 __attribute__((ext_vector_type(8)));   // 8 bf16 (4 VGPRs)
typedef float f32x4 __attribute__((ext_vector_type(4)));   // MFMA C/D frag

__device__ __forceinline__ short f2bf(float f) {          // fp32 -> bf16 (RNE)
    unsigned u = __float_as_uint(f);
    return (short)((u + 0x7fffu + ((u >> 16) & 1u)) >> 16);
}
__device__ __forceinline__ float bf2f(short s) {
    return __uint_as_float(((unsigned)(unsigned short)s) << 16);
}

// ---------------- Linear role: one wave computes 16 rows of h via MFMA -------
// hi/lo bf16 split both sides, 3 MFMAs per tile => fp32-level accuracy.
__device__ __forceinline__ void linear_role(
    int tile, int ntiles, int lane, int N,
    const float* __restrict__ x, const float* __restrict__ W,
    const float* __restrict__ b, const float* __restrict__ a2,
    __half* __restrict__ g16, float* __restrict__ es2)
{
    if (tile >= ntiles) return;
    int m = lane & 15, oct = lane >> 4;
    long rowbase = (long)tile * 16;

    s16x8 bh[2][4], bl[2][4];
    #pragma unroll
    for (int t = 0; t < 2; ++t) {
        const float* wrow = W + (long)(t * 16 + m) * DIN + oct * 8;
        #pragma unroll
        for (int kc = 0; kc < 4; ++kc) {
            float4 w0 = *(const float4*)(wrow + kc * 32);
            float4 w1 = *(const float4*)(wrow + kc * 32 + 4);
            float wf[8] = {w0.x, w0.y, w0.z, w0.w, w1.x, w1.y, w1.z, w1.w};
            #pragma unroll
            for (int j = 0; j < 8; ++j) {
                short hh = f2bf(wf[j]);
                bh[t][kc][j] = hh;
                bl[t][kc][j] = f2bf(wf[j] - bf2f(hh));
            }
        }
    }

    long lrow = rowbase + m; if (lrow > N - 1) lrow = N - 1;   // load clamp
    const float* xrow = x + lrow * DIN + oct * 8;
    f32x4 acc0 = {0.f, 0.f, 0.f, 0.f}, acc1 = {0.f, 0.f, 0.f, 0.f};
    #pragma unroll
    for (int kc = 0; kc < 4; ++kc) {
        float4 x0 = *(const float4*)(xrow + kc * 32);
        float4 x1 = *(const float4*)(xrow + kc * 32 + 4);
        float xf[8] = {x0.x, x0.y, x0.z, x0.w, x1.x, x1.y, x1.z, x1.w};
        s16x8 ah, al;
        #pragma unroll
        for (int j = 0; j < 8; ++j) {
            short hh = f2bf(xf[j]);
            ah[j] = hh;
            al[j] = f2bf(xf[j] - bf2f(hh));
        }
        acc0 = __builtin_amdgcn_mfma_f32_16x16x32_bf16(al, bh[0][kc], acc0, 0, 0, 0);
        acc0 = __builtin_amdgcn_mfma_f32_16x16x32_bf16(ah, bl[0][kc], acc0, 0, 0, 0);
        acc0 = __builtin_amdgcn_mfma_f32_16x16x32_bf16(ah, bh[0][kc], acc0, 0, 0, 0);
        acc1 = __builtin_amdgcn_mfma_f32_16x16x32_bf16(al, bh[1][kc], acc1, 0, 0, 0);
        acc1 = __builtin_amdgcn_mfma_f32_16x16x32_bf16(ah, bl[1][kc], acc1, 0, 0, 0);
        acc1 = __builtin_amdgcn_mfma_f32_16x16x32_bf16(ah, bh[1][kc], acc1, 0, 0, 0);
    }

    int c0 = m, c1 = 16 + m;
    float b0 = b[c0], b1 = b[c1], A0 = a2[c0], A1 = a2[c1];
    float hv0[4], hv1[4], sp[4];
    #pragma unroll
    for (int i = 0; i < 4; ++i) {
        hv0[i] = acc0[i] + b0;
        hv1[i] = acc1[i] + b1;
        float z0 = hv0[i] > 0.f ? hv0[i] : SLOPE * hv0[i];
        float z1 = hv1[i] > 0.f ? hv1[i] : SLOPE * hv1[i];
        sp[i] = z0 * A0 + z1 * A1;
    }
    #pragma unroll
    for (int off = 1; off <= 8; off <<= 1) {
        #pragma unroll
        for (int i = 0; i < 4; ++i) sp[i] += __shfl_xor(sp[i], off, 64);
    }
    #pragma unroll
    for (int i = 0; i < 4; ++i) {
        long r = rowbase + oct * 4 + i;
        if (r >= N) continue;
        float ev = __expf(sp[i]);              // shift-invariant softmax: no max pass
        g16[r * DOUT + c0] = __float2half(ev * hv0[i]);
        g16[r * DOUT + c1] = __float2half(ev * hv1[i]);
        if (m == 0) es2[r] = ev;
    }
}

// ---------------- Fused kernel: linear blocks + edge-binning blocks ----------
// Bin: group edges by src-bucket. Record = (src&127)<<17 | dst.
__global__ __launch_bounds__(256) void gat_fused(
    const float* __restrict__ x, const float* __restrict__ W,
    const float* __restrict__ b, const float* __restrict__ a2,
    const int* __restrict__ src, const int* __restrict__ dst,
    __half* __restrict__ g16, float* __restrict__ es2,
    unsigned* __restrict__ ebuf, int* __restrict__ gcursor,
    int N, int E, int ntiles, int nlin, int NB)
{
    if ((int)blockIdx.x < nlin) {
        int wave = threadIdx.x >> 6;
        int tile = blockIdx.x * 4 + wave;
        linear_role(tile, ntiles, threadIdx.x & 63, N, x, W, b, a2, g16, es2);
        return;
    }
    __shared__ int cnt[NBMAX];
    __shared__ int base[NBMAX];
    __shared__ int ssrc[TILE];        // stage src: read global once, use twice
    int tid = threadIdx.x;
    int tstart = (blockIdx.x - nlin) * TILE;

    for (int i = tid; i < NB; i += 256) cnt[i] = 0;
    __syncthreads();
    #pragma unroll 4
    for (int it = 0; it < TILE / 256; ++it) {
        int e = tstart + it * 256 + tid;
        int s = (e < E) ? src[e] : -1;
        ssrc[it * 256 + tid] = s;
        if (s >= 0) atomicAdd(&cnt[s >> BSHIFT], 1);
    }
    __syncthreads();
    for (int i = tid; i < NB; i += 256) {
        base[i] = atomicAdd(&gcursor[i], cnt[i]);
        cnt[i] = 0;
    }
    __syncthreads();
    #pragma unroll 4
    for (int it = 0; it < TILE / 256; ++it) {
        int e = tstart + it * 256 + tid;
        if (e < E) {
            int s = ssrc[it * 256 + tid];
            int bk = s >> BSHIFT;
            int pos = base[bk] + atomicAdd(&cnt[bk], 1);
            if (pos < CAP)
                ebuf[(size_t)bk * CAP + pos] = ((unsigned)(s & (BNODES - 1)) << 17)
                                             | (unsigned)dst[e];
        }
    }
}

// ---------------- Aggregate: one 512-thread block per bucket -----------------
// Records staged in LDS; 16 units x 8-way unrolled independent g16 gathers
// (~100k lines in flight device-wide); fp32 LDS accumulators (bank = col,
// 2-way aliasing only). 4 blocks/CU resident -> all 782 blocks co-resident.
__global__ __launch_bounds__(512) void gat_aggregate(
    const __half* __restrict__ g16, const float* __restrict__ es2,
    const unsigned* __restrict__ ebuf, const int* __restrict__ gcursor,
    float* __restrict__ out, int N)
{
    __shared__ float acc[BNODES * 32];   // 16 KB
    __shared__ float accd[BNODES];
    __shared__ unsigned rs[CAP];         // 12 KB record staging
    int tid = threadIdx.x;
    int bk = blockIdx.x;
    int cnt = gcursor[bk]; if (cnt > CAP) cnt = CAP;

    for (int i = tid; i < BNODES * 32; i += 512) acc[i] = 0.f;
    if (tid < BNODES) accd[tid] = 0.f;
    const unsigned* eb = ebuf + (size_t)bk * CAP;
    for (int r = tid; r < cnt; r += 512) rs[r] = eb[r];   // sequential stream
    __syncthreads();

    int unit = tid >> 5, col = tid & 31;          // 16 units of 32 lanes
    int ngrp = cnt >> 3;
    for (int grp = unit; grp < ngrp; grp += 16) {
        int gb = grp * 8;
        unsigned u[8];
        #pragma unroll
        for (int j = 0; j < 8; ++j) u[j] = rs[gb + j];    // LDS broadcast
        float gv[8];
        #pragma unroll
        for (int j = 0; j < 8; ++j)                        // 8 independent gathers
            gv[j] = __half2float(g16[(long)(u[j] & 0x1FFFFu) * DOUT + col]);
        #pragma unroll
        for (int j = 0; j < 8; ++j)
            atomicAdd(&acc[((u[j] >> 17) & 127u) * 32 + col], gv[j]);
        if (col == 0) {
            #pragma unroll
            for (int j = 0; j < 8; ++j)
                atomicAdd(&accd[(u[j] >> 17) & 127u], es2[u[j] & 0x1FFFFu]);
        }
    }
    for (int r = (ngrp << 3) + unit; r < cnt; r += 16) {   // tail
        unsigned u = rs[r];
        int dn = (int)(u & 0x1FFFFu), sl = (int)((u >> 17) & 127u);
        atomicAdd(&acc[sl * 32 + col], __half2float(g16[(long)dn * DOUT + col]));
        if (col == 0) atomicAdd(&accd[sl], es2[dn]);
    }
    __syncthreads();

    for (int sl = unit; sl < BNODES; sl += 16) {
        long node = (long)bk * BNODES + sl;
        if (node >= N) break;
        float gs = __half2float(g16[node * DOUT + col]);   // self-loop
        float d = accd[sl] + es2[node];
        out[node * DOUT + col] = (acc[sl * 32 + col] + gs) / d;
    }
}

extern "C" void kernel_launch(void* const* d_in, const int* in_sizes, int n_in,
                              void* d_out, int out_size, void* d_ws, size_t ws_size,
                              hipStream_t stream)
{
    const float* x  = (const float*)d_in[0];
    const int*   ei = (const int*)d_in[1];
    const float* W  = (const float*)d_in[2];
    const float* b  = (const float*)d_in[3];
    // d_in[4] = a1_w: unused — s1 cancels inside the segment softmax.
    const float* a2 = (const float*)d_in[5];
    float* out = (float*)d_out;

    int N = in_sizes[0] / DIN;
    int E = in_sizes[1] / 2;
    const int* src = ei;
    const int* dst = ei + E;

    int NB = (N + BNODES - 1) >> BSHIFT;      // 782

    char* ws = (char*)d_ws;
    __half*   g16    = (__half*)ws;   ws += (size_t)N * DOUT * sizeof(__half);
    float*    es2    = (float*)ws;    ws += (size_t)N * sizeof(float);
    int*      gcursor= (int*)ws;      ws += (size_t)NBMAX * sizeof(int);
    unsigned* ebuf   = (unsigned*)ws; ws += (size_t)NB * CAP * sizeof(unsigned);

    int ntiles = (N + 15) / 16;               // 6250
    int nlin   = (ntiles + 3) / 4;            // 1563 linear blocks (4 waves)
    int nbin   = (E + TILE - 1) / TILE;       // 391 bin blocks

    hipMemsetAsync(gcursor, 0, (size_t)NBMAX * sizeof(int), stream);
    gat_fused    <<<nlin + nbin, 256, 0, stream>>>(x, W, b, a2, src, dst,
                                                   g16, es2, ebuf, gcursor,
                                                   N, E, ntiles, nlin, NB);
    gat_aggregate<<<NB, 512, 0, stream>>>(g16, es2, ebuf, gcursor, out, N);
}